// Round 5
// baseline (864.396 us; speedup 1.0000x reference)
//
#include <hip/hip_runtime.h>
#include <stdint.h>

typedef unsigned short u16;
typedef unsigned int u32;

#define T_SEQ 1024
#define HID   2048
#define NH    32
#define HD    64
#define NCHUNK 16
#define INTER 5632

typedef __attribute__((ext_vector_type(8))) short b16x8;
typedef __attribute__((ext_vector_type(4))) float f32x4;

__device__ inline float bf2f(u16 u) { union { u32 i; float f; } v; v.i = ((u32)u) << 16; return v.f; }
__device__ inline u16 f2bf(float f) {
  union { float f; u32 i; } v; v.f = f;
  u32 u = v.i;
  return (u16)((u + 0x7FFFu + ((u >> 16) & 1u)) >> 16);  // RNE
}
__device__ inline float silu_f(float x) { return x / (1.f + __expf(-x)); }

// ---------------- fp32 -> bf16 all-weights conversion (one launch) ----------------
__global__ __launch_bounds__(256) void k_cvt_all(
    const float* __restrict__ s0, const float* __restrict__ s1, const float* __restrict__ s2,
    const float* __restrict__ s3, const float* __restrict__ s4, const float* __restrict__ s5,
    const float* __restrict__ s6,
    u16* __restrict__ d0, u16* __restrict__ d1, u16* __restrict__ d2, u16* __restrict__ d3,
    u16* __restrict__ d4, u16* __restrict__ d5, u16* __restrict__ d6) {
  int z = blockIdx.y;
  int n4 = (z < 4) ? (HID * HID / 4) : (INTER * HID / 4);
  int i = blockIdx.x * 256 + threadIdx.x;
  if (i >= n4) return;
  const float* s = (z == 0) ? s0 : (z == 1) ? s1 : (z == 2) ? s2 : (z == 3) ? s3
                   : (z == 4) ? s4 : (z == 5) ? s5 : s6;
  u16* d = (z == 0) ? d0 : (z == 1) ? d1 : (z == 2) ? d2 : (z == 3) ? d3
           : (z == 4) ? d4 : (z == 5) ? d5 : d6;
  float4 v = ((const float4*)s)[i];
  u32 lo = (u32)f2bf(v.x) | ((u32)f2bf(v.y) << 16);
  u32 hi = (u32)f2bf(v.z) | ((u32)f2bf(v.w) << 16);
  ((uint2*)d)[i] = make_uint2(lo, hi);
}

// ---------------- RMSNorm: fp32 in -> bf16 out ----------------
__global__ __launch_bounds__(256) void k_rms(const float* __restrict__ x, const float* __restrict__ w,
                                             u16* __restrict__ out) {
  int row = blockIdx.x, tid = threadIdx.x;
  const float* xr = x + (size_t)row * HID;
  float4 v0 = ((const float4*)xr)[tid];
  float4 v1 = ((const float4*)xr)[tid + 256];
  float ss = v0.x * v0.x + v0.y * v0.y + v0.z * v0.z + v0.w * v0.w +
             v1.x * v1.x + v1.y * v1.y + v1.z * v1.z + v1.w * v1.w;
  for (int m = 32; m; m >>= 1) ss += __shfl_xor(ss, m, 64);
  __shared__ float wsum[4];
  if ((tid & 63) == 0) wsum[tid >> 6] = ss;
  __syncthreads();
  float tot = wsum[0] + wsum[1] + wsum[2] + wsum[3];
  float sc = rsqrtf(tot / (float)HID + 1e-6f);
  float4 w0 = ((const float4*)w)[tid];
  float4 w1 = ((const float4*)w)[tid + 256];
  u32 lo, hi;
  lo = (u32)f2bf(v0.x * sc * w0.x) | ((u32)f2bf(v0.y * sc * w0.y) << 16);
  hi = (u32)f2bf(v0.z * sc * w0.z) | ((u32)f2bf(v0.w * sc * w0.w) << 16);
  ((uint2*)out)[(size_t)row * 512 + tid] = make_uint2(lo, hi);
  lo = (u32)f2bf(v1.x * sc * w1.x) | ((u32)f2bf(v1.y * sc * w1.y) << 16);
  hi = (u32)f2bf(v1.z * sc * w1.z) | ((u32)f2bf(v1.w * sc * w1.w) << 16);
  ((uint2*)out)[(size_t)row * 512 + tid + 256] = make_uint2(lo, hi);
}

// ---------------- split-K bf16 GEMM, NO-LDS register-direct fragments, atomicAdd epilogue ----
// Fragments loaded straight from global (B^T layout makes both A and B frags 16B/lane
// contiguous). No __syncthreads in K-loop -> waves free-run, fine-grained vmcnt pipelining.
// Full unroll: per-iter offsets are compile-time immediates.
template <int NIT>
__global__ __launch_bounds__(256) void k_gemm_sk(
    const u16* __restrict__ A,
    const u16* __restrict__ B0, const u16* __restrict__ B1, const u16* __restrict__ B2,
    float* __restrict__ C0, float* __restrict__ C1, float* __restrict__ C2,
    const float* __restrict__ resid, int N, int Kf, int nslice) {
  int mat = blockIdx.z / nslice, slice = blockIdx.z % nslice;
  const u16* Bp = (mat == 0) ? B0 : (mat == 1 ? B1 : B2);
  float* Cp = (mat == 0) ? C0 : (mat == 1 ? C1 : C2);
  int tid = threadIdx.x;
  int m0 = blockIdx.y * 128, n0 = blockIdx.x * 128;
  int lane = tid & 63, wv = tid >> 6, wr = wv >> 1, wc = wv & 1;
  int lrow = lane & 15, quad = lane >> 4;
  int kb = slice * (NIT * 32);
  const u16* Ar[4];
  const u16* Br[4];
#pragma unroll
  for (int i = 0; i < 4; ++i) {
    Ar[i] = A + (size_t)(m0 + wr * 64 + i * 16 + lrow) * Kf + kb + quad * 8;
    Br[i] = Bp + (size_t)(n0 + wc * 64 + i * 16 + lrow) * Kf + kb + quad * 8;
  }
  f32x4 acc[4][4];
#pragma unroll
  for (int i = 0; i < 4; ++i)
#pragma unroll
    for (int j = 0; j < 4; ++j) acc[i][j] = (f32x4){0.f, 0.f, 0.f, 0.f};

  b16x8 af[2][4], bfr[2][4];
#pragma unroll
  for (int i = 0; i < 4; ++i) {
    af[0][i] = *(const b16x8*)(Ar[i]);
    bfr[0][i] = *(const b16x8*)(Br[i]);
  }
#pragma unroll
  for (int it = 0; it < NIT; ++it) {
    const int p = it & 1;
    if (it + 1 < NIT) {
#pragma unroll
      for (int i = 0; i < 4; ++i) {
        af[p ^ 1][i] = *(const b16x8*)(Ar[i] + (it + 1) * 32);
        bfr[p ^ 1][i] = *(const b16x8*)(Br[i] + (it + 1) * 32);
      }
    }
#pragma unroll
    for (int i = 0; i < 4; ++i)
#pragma unroll
      for (int j = 0; j < 4; ++j)
        acc[i][j] = __builtin_amdgcn_mfma_f32_16x16x32_bf16(af[p][i], bfr[p][j], acc[i][j], 0, 0, 0);
  }
#pragma unroll
  for (int i = 0; i < 4; ++i)
#pragma unroll
    for (int j = 0; j < 4; ++j)
#pragma unroll
      for (int r = 0; r < 4; ++r) {
        int row = m0 + wr * 64 + i * 16 + quad * 4 + r;
        int col = n0 + wc * 64 + j * 16 + lrow;
        float val = acc[i][j][r];
        if (slice == 0 && resid) val += resid[(size_t)row * N + col];
        atomicAdd(&Cp[(size_t)row * N + col], val);
      }
}

// ---------------- fused gate/up GEMM + swiglu, NO-LDS, XCD-aware swizzle ----------------
__global__ __launch_bounds__(256) void k_gemm_gu(
    const u16* __restrict__ A, const u16* __restrict__ Bg, const u16* __restrict__ Bu,
    u16* __restrict__ D) {
  int flat = blockIdx.x;
  int xcd = flat & 7, idx = flat >> 3;
  int n = xcd + 8 * (idx >> 3), m = idx & 7;
  if (n >= INTER / 128) return;
  int tid = threadIdx.x;
  int m0 = m * 128, n0 = n * 128;
  int lane = tid & 63, wv = tid >> 6, wr = wv >> 1, wc = wv & 1;
  int lrow = lane & 15, quad = lane >> 4;
  const u16* Ar[4];
  const u16* Gr[4];
  const u16* Ur[4];
#pragma unroll
  for (int i = 0; i < 4; ++i) {
    Ar[i] = A + (size_t)(m0 + wr * 64 + i * 16 + lrow) * HID + quad * 8;
    Gr[i] = Bg + (size_t)(n0 + wc * 64 + i * 16 + lrow) * HID + quad * 8;
    Ur[i] = Bu + (size_t)(n0 + wc * 64 + i * 16 + lrow) * HID + quad * 8;
  }
  f32x4 ag[4][4], au[4][4];
#pragma unroll
  for (int i = 0; i < 4; ++i)
#pragma unroll
    for (int j = 0; j < 4; ++j) { ag[i][j] = (f32x4){0.f, 0.f, 0.f, 0.f}; au[i][j] = (f32x4){0.f, 0.f, 0.f, 0.f}; }

#pragma unroll
  for (int it = 0; it < HID / 32; ++it) {
    b16x8 af[4], gf[4], uf[4];
#pragma unroll
    for (int i = 0; i < 4; ++i) {
      af[i] = *(const b16x8*)(Ar[i] + it * 32);
      gf[i] = *(const b16x8*)(Gr[i] + it * 32);
      uf[i] = *(const b16x8*)(Ur[i] + it * 32);
    }
#pragma unroll
    for (int i = 0; i < 4; ++i)
#pragma unroll
      for (int j = 0; j < 4; ++j) {
        ag[i][j] = __builtin_amdgcn_mfma_f32_16x16x32_bf16(af[i], gf[j], ag[i][j], 0, 0, 0);
        au[i][j] = __builtin_amdgcn_mfma_f32_16x16x32_bf16(af[i], uf[j], au[i][j], 0, 0, 0);
      }
  }
#pragma unroll
  for (int i = 0; i < 4; ++i)
#pragma unroll
    for (int j = 0; j < 4; ++j)
#pragma unroll
      for (int r = 0; r < 4; ++r) {
        int row = m0 + wr * 64 + i * 16 + quad * 4 + r;
        int col = n0 + wc * 64 + j * 16 + lrow;
        D[(size_t)row * INTER + col] = f2bf(silu_f(ag[i][j][r]) * au[i][j][r]);
      }
}

// ---------------- beta = sigmoid(h @ Wbeta^T) ----------------
__global__ __launch_bounds__(256) void k_beta(const u16* __restrict__ hbf, const float* __restrict__ Wb,
                                              float* __restrict__ beta) {
  __shared__ __align__(16) float hr[HID];
  __shared__ float red[256];
  int t = blockIdx.x, tid = threadIdx.x;
#pragma unroll
  for (int i = 0; i < 8; ++i) {
    int c = i * 256 + tid;
    hr[c] = bf2f(hbf[(size_t)t * HID + c]);
  }
  __syncthreads();
  int head = tid >> 3, j = tid & 7;
  const float* wrow = Wb + (size_t)head * HID + j * 256;
  const float* hs = hr + j * 256;
  float acc = 0.f;
#pragma unroll 16
  for (int c = 0; c < 256; c += 4) {
    float4 wv = *(const float4*)&wrow[c];
    float4 hv = *(const float4*)&hs[c];
    acc += hv.x * wv.x + hv.y * wv.y + hv.z * wv.z + hv.w * wv.w;
  }
  red[tid] = acc;
  __syncthreads();
  if (tid < 32) {
    float s = 0.f;
#pragma unroll
    for (int i = 0; i < 8; ++i) s += red[tid * 8 + i];
    beta[(size_t)t * NH + tid] = 1.f / (1.f + __expf(-s));
  }
}

// ---------------- causal depthwise conv (K=4) + silu(silu) (+ l2norm for q,k) ----------------
__global__ __launch_bounds__(256) void k_conv(const float* __restrict__ proj,
                                              const float* __restrict__ cw0, const float* __restrict__ cw1,
                                              const float* __restrict__ cw2, float* __restrict__ outp) {
  int z = blockIdx.z;
  const float* src = proj + (size_t)z * T_SEQ * HID;
  float* dst = outp + (size_t)z * T_SEQ * HID;
  const float* cw = (z == 0) ? cw0 : (z == 1 ? cw1 : cw2);
  bool l2 = (z < 2);
  int c = threadIdx.x & 63, wr = threadIdx.x >> 6;
  int head = blockIdx.y;
  int ch = head * 64 + c;
  int t0 = blockIdx.x * 64 + wr * 16;
  float4 w = ((const float4*)cw)[ch];
  float xm3 = (t0 >= 3) ? src[(size_t)(t0 - 3) * HID + ch] : 0.f;
  float xm2 = (t0 >= 2) ? src[(size_t)(t0 - 2) * HID + ch] : 0.f;
  float xm1 = (t0 >= 1) ? src[(size_t)(t0 - 1) * HID + ch] : 0.f;
  for (int i = 0; i < 16; ++i) {
    int t = t0 + i;
    float x0 = src[(size_t)t * HID + ch];
    float zv = xm3 * w.x + xm2 * w.y + xm1 * w.z + x0 * w.w;
    float s = silu_f(silu_f(zv));
    if (l2) {
      float ss = s * s;
      for (int m = 32; m; m >>= 1) ss += __shfl_xor(ss, m, 64);
      float n = sqrtf(ss);
      s = s / fmaxf(n, 1e-12f);
    }
    dst[(size_t)t * HID + ch] = s;
    xm3 = xm2; xm2 = xm1; xm1 = x0;
  }
}

// ---------------- Phase A ----------------
__global__ __launch_bounds__(256) void k_phaseA(
    const float* __restrict__ qp, const float* __restrict__ kp, const float* __restrict__ vp,
    const float* __restrict__ beta,
    u16* __restrict__ negWbf, u16* __restrict__ Uvbf, u16* __restrict__ Ktbf,
    u16* __restrict__ Qbf, u16* __restrict__ Pbf) {
  int cx = blockIdx.x, h = blockIdx.y;
  __shared__ __align__(16) u16 Kst[64 * 72];
  __shared__ __align__(16) u16 Qst[64 * 72];
  __shared__ __align__(16) float Af[64 * 68];
  __shared__ float bet[64];
  int tid = threadIdx.x;
  int t0 = cx * 64;
#pragma unroll
  for (int i = 0; i < 16; ++i) {
    int idx = i * 256 + tid, s = idx >> 6, d = idx & 63;
    size_t g = (size_t)(t0 + s) * HID + h * 64 + d;
    Kst[s * 72 + d] = f2bf(kp[g]);
    Qst[s * 72 + d] = f2bf(qp[g]);
  }
  if (tid < 64) bet[tid] = beta[(size_t)(t0 + tid) * NH + h];
  __syncthreads();
  int lane = tid & 63, wv = tid >> 6, lrow = lane & 15, quad = lane >> 4;
  f32x4 accA[4], accP[4];
#pragma unroll
  for (int i = 0; i < 4; ++i) { accA[i] = (f32x4){0.f, 0.f, 0.f, 0.f}; accP[i] = (f32x4){0.f, 0.f, 0.f, 0.f}; }
#pragma unroll
  for (int ks = 0; ks < 2; ++ks) {
    b16x8 bk = *(const b16x8*)&Kst[(wv * 16 + lrow) * 72 + ks * 32 + quad * 8];
#pragma unroll
    for (int i = 0; i < 4; ++i) {
      b16x8 ak = *(const b16x8*)&Kst[(i * 16 + lrow) * 72 + ks * 32 + quad * 8];
      b16x8 aq = *(const b16x8*)&Qst[(i * 16 + lrow) * 72 + ks * 32 + quad * 8];
      accA[i] = __builtin_amdgcn_mfma_f32_16x16x32_bf16(ak, bk, accA[i], 0, 0, 0);
      accP[i] = __builtin_amdgcn_mfma_f32_16x16x32_bf16(aq, bk, accP[i], 0, 0, 0);
    }
  }
  size_t cb2 = ((size_t)h * NCHUNK + cx) * 4096;
#pragma unroll
  for (int i = 0; i < 4; ++i)
#pragma unroll
    for (int r = 0; r < 4; ++r) {
      int srow = i * 16 + quad * 4 + r, col = wv * 16 + lrow;
      Af[srow * 68 + col] = (col < srow) ? accA[i][r] * bet[srow] : 0.f;
      Pbf[cb2 + srow * 64 + col] = f2bf((col <= srow) ? accP[i][r] : 0.f);
    }
  __syncthreads();
  if (wv < 2) {
    int c = lane;
    float x[64];
    if (wv == 0) {
#pragma unroll
      for (int s = 0; s < 64; ++s) x[s] = bet[s] * bf2f(Kst[s * 72 + c]);
    } else {
#pragma unroll
      for (int s = 0; s < 64; ++s) x[s] = bet[s] * vp[(size_t)(t0 + s) * HID + h * 64 + c];
    }
#pragma unroll
    for (int s = 1; s < 64; ++s) {
      float a = 0.f;
#pragma unroll
      for (int r = 0; r < (s & ~3); r += 4) {
        float4 av = *(const float4*)&Af[s * 68 + r];
        a += av.x * x[r] + av.y * x[r + 1] + av.z * x[r + 2] + av.w * x[r + 3];
      }
#pragma unroll
      for (int r = (s & ~3); r < s; ++r) a += Af[s * 68 + r] * x[r];
      x[s] -= a;
    }
    if (wv == 0) {
#pragma unroll
      for (int s = 0; s < 64; ++s) negWbf[cb2 + s * 64 + c] = f2bf(-x[s]);
    } else {
#pragma unroll
      for (int s = 0; s < 64; ++s) Uvbf[cb2 + s * 64 + c] = f2bf(x[s]);
    }
  } else if (wv == 2) {
#pragma unroll
    for (int it = 0; it < 8; ++it) {
      int cidx = it * 64 + lane, s = cidx >> 3, d0 = (cidx & 7) * 8;
      *(uint4*)&Qbf[cb2 + s * 64 + d0] = *(const uint4*)&Qst[s * 72 + d0];
    }
  } else {
#pragma unroll
    for (int it = 0; it < 8; ++it) {
      int cidx = it * 64 + lane, d = cidx >> 3, s0 = (cidx & 7) * 8;
      u16 tmp[8];
#pragma unroll
      for (int j = 0; j < 8; ++j) tmp[j] = Kst[(s0 + j) * 72 + d];
      *(uint4*)&Ktbf[cb2 + d * 64 + s0] = *(const uint4*)tmp;
    }
  }
}

// ---------------- Phase B1: serial per head ----------------
__global__ __launch_bounds__(256) void k_phaseB1(
    const u16* __restrict__ negWbf, const u16* __restrict__ Uvbf, const u16* __restrict__ Ktbf,
    u16* __restrict__ Utws, u16* __restrict__ Sws, float* __restrict__ Sout) {
  int h = blockIdx.x, tid = threadIdx.x;
  __shared__ __align__(16) u16 S0b[2][64 * 72];
  __shared__ __align__(16) u16 Ut[64 * 72];
  int lane = tid & 63, wv = tid >> 6, lrow = lane & 15, quad = lane >> 4;
#pragma unroll
  for (int i = 0; i < 16; ++i) {
    int idx = i * 256 + tid;
    S0b[0][(idx >> 6) * 72 + (idx & 63)] = 0;
  }
  f32x4 aS[4];
#pragma unroll
  for (int i = 0; i < 4; ++i) aS[i] = (f32x4){0.f, 0.f, 0.f, 0.f};

  b16x8 Wf[2][4][2]; b16x8 Ktf[2][2]; u16 Uvr[2][4][4];
  size_t hb = (size_t)h * NCHUNK * 4096;
  {
    size_t cb2 = hb;
#pragma unroll
    for (int i = 0; i < 4; ++i)
#pragma unroll
      for (int ks = 0; ks < 2; ++ks)
        Wf[0][i][ks] = *(const b16x8*)&negWbf[cb2 + (i * 16 + lrow) * 64 + ks * 32 + quad * 8];
#pragma unroll
    for (int ks = 0; ks < 2; ++ks)
      Ktf[0][ks] = *(const b16x8*)&Ktbf[cb2 + (wv * 16 + lrow) * 64 + ks * 32 + quad * 8];
#pragma unroll
    for (int i = 0; i < 4; ++i)
#pragma unroll
      for (int r = 0; r < 4; ++r)
        Uvr[0][i][r] = Uvbf[cb2 + (i * 16 + quad * 4 + r) * 64 + wv * 16 + lrow];
  }
  __syncthreads();
#pragma unroll
  for (int cx = 0; cx < NCHUNK; ++cx) {
    const int p = cx & 1, q = p ^ 1;
    size_t cb2 = hb + (size_t)cx * 4096;
    if (cx > 0) {
#pragma unroll
      for (int i = 0; i < 2; ++i) {
        int cidx = i * 256 + tid, dv = cidx >> 3, s0 = (cidx & 7) * 8;
        *(uint4*)&Sws[cb2 + dv * 64 + s0] = *(const uint4*)&S0b[p][dv * 72 + s0];
      }
    }
    if (cx + 1 < NCHUNK) {
      size_t cbn = cb2 + 4096;
#pragma unroll
      for (int i = 0; i < 4; ++i)
#pragma unroll
        for (int ks = 0; ks < 2; ++ks)
          Wf[q][i][ks] = *(const b16x8*)&negWbf[cbn + (i * 16 + lrow) * 64 + ks * 32 + quad * 8];
#pragma unroll
      for (int ks = 0; ks < 2; ++ks)
        Ktf[q][ks] = *(const b16x8*)&Ktbf[cbn + (wv * 16 + lrow) * 64 + ks * 32 + quad * 8];
#pragma unroll
      for (int i = 0; i < 4; ++i)
#pragma unroll
        for (int r = 0; r < 4; ++r)
          Uvr[q][i][r] = Uvbf[cbn + (i * 16 + quad * 4 + r) * 64 + wv * 16 + lrow];
    }
    f32x4 aU[4];
#pragma unroll
    for (int i = 0; i < 4; ++i)
#pragma unroll
      for (int r = 0; r < 4; ++r) aU[i][r] = bf2f(Uvr[p][i][r]);
#pragma unroll
    for (int ks = 0; ks < 2; ++ks) {
      b16x8 bS = *(const b16x8*)&S0b[p][(wv * 16 + lrow) * 72 + ks * 32 + quad * 8];
#pragma unroll
      for (int i = 0; i < 4; ++i)
        aU[i] = __builtin_amdgcn_mfma_f32_16x16x32_bf16(Wf[p][i][ks], bS, aU[i], 0, 0, 0);
    }
#pragma unroll
    for (int i = 0; i < 4; ++i)
#pragma unroll
      for (int r = 0; r < 4; ++r) {
        int s = i * 16 + quad * 4 + r, dv = wv * 16 + lrow;
        Ut[dv * 72 + s] = f2bf(aU[i][r]);
      }
    __syncthreads();
#pragma unroll
    for (int i = 0; i < 2; ++i) {
      int cidx = i * 256 + tid, dv = cidx >> 3, s0 = (cidx & 7) * 8;
      *(uint4*)&Utws[cb2 + dv * 64 + s0] = *(const uint4*)&Ut[dv * 72 + s0];
    }
#pragma unroll
    for (int ks = 0; ks < 2; ++ks) {
#pragma unroll
      for (int i = 0; i < 4; ++i) {
        b16x8 a = *(const b16x8*)&Ut[(i * 16 + lrow) * 72 + ks * 32 + quad * 8];
        aS[i] = __builtin_amdgcn_mfma_f32_16x16x32_bf16(a, Ktf[p][ks], aS[i], 0, 0, 0);
      }
    }
#pragma unroll
    for (int i = 0; i < 4; ++i)
#pragma unroll
      for (int r = 0; r < 4; ++r) {
        int dv = i * 16 + quad * 4 + r, dk = wv * 16 + lrow;
        S0b[q][dv * 72 + dk] = f2bf(aS[i][r]);
      }
    __syncthreads();
  }
#pragma unroll
  for (int i = 0; i < 4; ++i)
#pragma unroll
    for (int r = 0; r < 4; ++r) {
      int dv = i * 16 + quad * 4 + r, dk = wv * 16 + lrow;
      Sout[(size_t)h * 4096 + dv * 64 + dk] = aS[i][r];
    }
}

// ---------------- Phase B2: parallel O = Q S^T + P U ----------------
__global__ __launch_bounds__(256) void k_phaseB2(
    const u16* __restrict__ Qbf, const u16* __restrict__ Pbf,
    const u16* __restrict__ Utws, const u16* __restrict__ Sws, float* __restrict__ o) {
  int cx = blockIdx.x, h = blockIdx.y, tid = threadIdx.x;
  int lane = tid & 63, wv = tid >> 6, lrow = lane & 15, quad = lane >> 4;
  size_t cb2 = ((size_t)h * NCHUNK + cx) * 4096;
  f32x4 aO[4];
#pragma unroll
  for (int i = 0; i < 4; ++i) aO[i] = (f32x4){0.f, 0.f, 0.f, 0.f};
#pragma unroll
  for (int ks = 0; ks < 2; ++ks) {
    b16x8 Uf = *(const b16x8*)&Utws[cb2 + (wv * 16 + lrow) * 64 + ks * 32 + quad * 8];
#pragma unroll
    for (int i = 0; i < 4; ++i) {
      b16x8 Pf = *(const b16x8*)&Pbf[cb2 + (i * 16 + lrow) * 64 + ks * 32 + quad * 8];
      aO[i] = __builtin_amdgcn_mfma_f32_16x16x32_bf16(Pf, Uf, aO[i], 0, 0, 0);
    }
  }
  if (cx > 0) {
#pragma unroll
    for (int ks = 0; ks < 2; ++ks) {
      b16x8 Sf = *(const b16x8*)&Sws[cb2 + (wv * 16 + lrow) * 64 + ks * 32 + quad * 8];
#pragma unroll
      for (int i = 0; i < 4; ++i) {
        b16x8 Qf = *(const b16x8*)&Qbf[cb2 + (i * 16 + lrow) * 64 + ks * 32 + quad * 8];
        aO[i] = __builtin_amdgcn_mfma_f32_16x16x32_bf16(Qf, Sf, aO[i], 0, 0, 0);
      }
    }
  }
  int t0 = cx * 64;
#pragma unroll
  for (int i = 0; i < 4; ++i)
#pragma unroll
    for (int r = 0; r < 4; ++r)
      o[(size_t)(t0 + i * 16 + quad * 4 + r) * HID + h * 64 + wv * 16 + lrow] = aO[i][r];
}

extern "C" void kernel_launch(void* const* d_in, const int* in_sizes, int n_in,
                              void* d_out, int out_size, void* d_ws, size_t ws_size,
                              hipStream_t stream) {
  const float* x     = (const float*)d_in[0];
  const float* anw   = (const float*)d_in[1];
  const float* Wq    = (const float*)d_in[2];
  const float* Wk    = (const float*)d_in[3];
  const float* Wv    = (const float*)d_in[4];
  const float* convq = (const float*)d_in[5];
  const float* convk = (const float*)d_in[6];
  const float* convv = (const float*)d_in[7];
  const float* Wbeta = (const float*)d_in[8];
  const float* onw   = (const float*)d_in[9];
  const float* Wout  = (const float*)d_in[10];
  const float* mnw   = (const float*)d_in[11];
  const float* Wgate = (const float*)d_in[12];
  const float* Wup   = (const float*)d_in[13];
  const float* Wdown = (const float*)d_in[14];
  float* out = (float*)d_out;

  const size_t TH = (size_t)T_SEQ * HID;
  const size_t SCAN = (size_t)NH * NCHUNK * 4096;
  char* wsb = (char*)d_ws;
  size_t off = 0;
  auto alloc = [&](size_t bytes) -> void* {
    void* p = wsb + off;
    off += (bytes + 255) & ~(size_t)255;
    return p;
  };
  u16* wq_bf    = (u16*)alloc((size_t)HID * HID * 2);
  u16* wk_bf    = (u16*)alloc((size_t)HID * HID * 2);
  u16* wv_bf    = (u16*)alloc((size_t)HID * HID * 2);
  u16* wout_bf  = (u16*)alloc((size_t)HID * HID * 2);
  u16* wgate_bf = (u16*)alloc((size_t)INTER * HID * 2);
  u16* wup_bf   = (u16*)alloc((size_t)INTER * HID * 2);
  u16* wdown_bf = (u16*)alloc((size_t)HID * INTER * 2);
  u16* actbf    = (u16*)alloc(TH * 2);
  float* qkv_proj = (float*)alloc(3 * TH * 4);   // aliased later: obuf
  float* qkvpost  = (float*)alloc(3 * TH * 4);
  float* betab    = (float*)alloc((size_t)T_SEQ * NH * 4);
  u16* negWbf = (u16*)alloc(SCAN * 2);           // aliased later by g_bf
  u16* Uvbf   = (u16*)alloc(SCAN * 2);
  u16* Ktbf   = (u16*)alloc(SCAN * 2);
  u16* Qbf    = (u16*)alloc(SCAN * 2);
  u16* Pbf    = (u16*)alloc(SCAN * 2);
  u16* Utws   = (u16*)alloc(SCAN * 2);
  u16* Sws    = (u16*)alloc(SCAN * 2);
  float* x1   = (float*)alloc(TH * 4);
  float* obuf = qkv_proj;   // qkv_proj dead after conv
  u16* g_bf   = negWbf;     // scan buffers dead after B2 (11.5MB < 3x4.19MB)

  // ---- zero all atomic targets up front ----
  hipMemsetAsync(qkv_proj, 0, 3 * TH * 4, stream);
  hipMemsetAsync(x1, 0, TH * 4, stream);
  hipMemsetAsync(out, 0, TH * 4, stream);

  // ---- all weight conversions in one launch ----
  k_cvt_all<<<dim3(INTER * HID / 4 / 256, 7), 256, 0, stream>>>(
      Wq, Wk, Wv, Wout, Wgate, Wup, Wdown,
      wq_bf, wk_bf, wv_bf, wout_bf, wgate_bf, wup_bf, wdown_bf);

  k_rms<<<dim3(T_SEQ), 256, 0, stream>>>(x, anw, actbf);
  // qkv projections: splitK=2 (768 blocks), K-slice 1024 = 32 iters
  k_gemm_sk<32><<<dim3(HID / 128, T_SEQ / 128, 6), 256, 0, stream>>>(
      actbf, wq_bf, wk_bf, wv_bf, qkv_proj, qkv_proj + TH, qkv_proj + 2 * TH, nullptr,
      HID, HID, 2);
  k_beta<<<dim3(T_SEQ), 256, 0, stream>>>(actbf, Wbeta, betab);
  k_conv<<<dim3(T_SEQ / 64, NH, 3), 256, 0, stream>>>(qkv_proj, convq, convk, convv, qkvpost);
  k_phaseA<<<dim3(NCHUNK, NH), 256, 0, stream>>>(
      qkvpost, qkvpost + TH, qkvpost + 2 * TH, betab, negWbf, Uvbf, Ktbf, Qbf, Pbf);
  k_phaseB1<<<dim3(NH), 256, 0, stream>>>(negWbf, Uvbf, Ktbf, Utws, Sws, out + TH);
  k_phaseB2<<<dim3(NCHUNK, NH), 256, 0, stream>>>(Qbf, Pbf, Utws, Sws, obuf);
  k_rms<<<dim3(T_SEQ), 256, 0, stream>>>(obuf, onw, actbf);
  // out projection: splitK=4 (512 blocks), K-slice 512 = 16 iters, resid=x
  k_gemm_sk<16><<<dim3(HID / 128, T_SEQ / 128, 4), 256, 0, stream>>>(
      actbf, wout_bf, wout_bf, wout_bf, x1, x1, x1, x, HID, HID, 4);
  k_rms<<<dim3(T_SEQ), 256, 0, stream>>>(x1, mnw, actbf);
  // fused gate/up + swiglu -> bf16 (384-block XCD-swizzled grid)
  k_gemm_gu<<<dim3(384), 256, 0, stream>>>(actbf, wgate_bf, wup_bf, g_bf);
  // down projection: splitK=4 (512 blocks), K-slice 1408 = 44 iters, resid=x1
  k_gemm_sk<44><<<dim3(HID / 128, T_SEQ / 128, 4), 256, 0, stream>>>(
      g_bf, wdown_bf, wdown_bf, wdown_bf, out, out, out, x1, HID, INTER, 4);
}

// Round 6
// 631.520 us; speedup vs baseline: 1.3688x; 1.3688x over previous
//
#include <hip/hip_runtime.h>
#include <stdint.h>

typedef unsigned short u16;
typedef unsigned int u32;

#define T_SEQ 1024
#define HID   2048
#define NH    32
#define HD    64
#define NCHUNK 16
#define INTER 5632

typedef __attribute__((ext_vector_type(8))) short b16x8;
typedef __attribute__((ext_vector_type(4))) float f32x4;

__device__ inline float bf2f(u16 u) { union { u32 i; float f; } v; v.i = ((u32)u) << 16; return v.f; }
__device__ inline u16 f2bf(float f) {
  union { float f; u32 i; } v; v.f = f;
  u32 u = v.i;
  return (u16)((u + 0x7FFFu + ((u >> 16) & 1u)) >> 16);  // RNE
}
__device__ inline float silu_f(float x) { return x / (1.f + __expf(-x)); }

typedef __attribute__((address_space(1))) const unsigned int as1_u32;
typedef __attribute__((address_space(3))) unsigned int as3_u32;
__device__ inline void gl_lds16(const void* g, void* l) {
  __builtin_amdgcn_global_load_lds((as1_u32*)g, (as3_u32*)l, 16, 0, 0);
}

// ---------------- fp32 -> bf16 all-weights conversion (one launch) ----------------
__global__ __launch_bounds__(256) void k_cvt_all(
    const float* __restrict__ s0, const float* __restrict__ s1, const float* __restrict__ s2,
    const float* __restrict__ s3, const float* __restrict__ s4, const float* __restrict__ s5,
    const float* __restrict__ s6,
    u16* __restrict__ d0, u16* __restrict__ d1, u16* __restrict__ d2, u16* __restrict__ d3,
    u16* __restrict__ d4, u16* __restrict__ d5, u16* __restrict__ d6) {
  int z = blockIdx.y;
  int n4 = (z < 4) ? (HID * HID / 4) : (INTER * HID / 4);
  int i = blockIdx.x * 256 + threadIdx.x;
  if (i >= n4) return;
  const float* s = (z == 0) ? s0 : (z == 1) ? s1 : (z == 2) ? s2 : (z == 3) ? s3
                   : (z == 4) ? s4 : (z == 5) ? s5 : s6;
  u16* d = (z == 0) ? d0 : (z == 1) ? d1 : (z == 2) ? d2 : (z == 3) ? d3
           : (z == 4) ? d4 : (z == 5) ? d5 : d6;
  float4 v = ((const float4*)s)[i];
  u32 lo = (u32)f2bf(v.x) | ((u32)f2bf(v.y) << 16);
  u32 hi = (u32)f2bf(v.z) | ((u32)f2bf(v.w) << 16);
  ((uint2*)d)[i] = make_uint2(lo, hi);
}

// ---------------- RMSNorm: fp32 in -> bf16 out ----------------
__global__ __launch_bounds__(256) void k_rms(const float* __restrict__ x, const float* __restrict__ w,
                                             u16* __restrict__ out) {
  int row = blockIdx.x, tid = threadIdx.x;
  const float* xr = x + (size_t)row * HID;
  float4 v0 = ((const float4*)xr)[tid];
  float4 v1 = ((const float4*)xr)[tid + 256];
  float ss = v0.x * v0.x + v0.y * v0.y + v0.z * v0.z + v0.w * v0.w +
             v1.x * v1.x + v1.y * v1.y + v1.z * v1.z + v1.w * v1.w;
  for (int m = 32; m; m >>= 1) ss += __shfl_xor(ss, m, 64);
  __shared__ float wsum[4];
  if ((tid & 63) == 0) wsum[tid >> 6] = ss;
  __syncthreads();
  float tot = wsum[0] + wsum[1] + wsum[2] + wsum[3];
  float sc = rsqrtf(tot / (float)HID + 1e-6f);
  float4 w0 = ((const float4*)w)[tid];
  float4 w1 = ((const float4*)w)[tid + 256];
  u32 lo, hi;
  lo = (u32)f2bf(v0.x * sc * w0.x) | ((u32)f2bf(v0.y * sc * w0.y) << 16);
  hi = (u32)f2bf(v0.z * sc * w0.z) | ((u32)f2bf(v0.w * sc * w0.w) << 16);
  ((uint2*)out)[(size_t)row * 512 + tid] = make_uint2(lo, hi);
  lo = (u32)f2bf(v1.x * sc * w1.x) | ((u32)f2bf(v1.y * sc * w1.y) << 16);
  hi = (u32)f2bf(v1.z * sc * w1.z) | ((u32)f2bf(v1.w * sc * w1.w) << 16);
  ((uint2*)out)[(size_t)row * 512 + tid + 256] = make_uint2(lo, hi);
}

// ---------------- split-K bf16 GEMM, double-buffered LDS prefetch, atomicAdd fp32 epilogue ----
__global__ __launch_bounds__(256) void k_gemm_sk(
    const u16* __restrict__ A,
    const u16* __restrict__ B0, const u16* __restrict__ B1, const u16* __restrict__ B2,
    float* __restrict__ C0, float* __restrict__ C1, float* __restrict__ C2,
    const float* __restrict__ resid, int M, int N, int Kf, int KS, int nslice) {
  int mat = blockIdx.z / nslice, slice = blockIdx.z % nslice;
  const u16* Bp = (mat == 0) ? B0 : (mat == 1 ? B1 : B2);
  float* Cp = (mat == 0) ? C0 : (mat == 1 ? C1 : C2);
  __shared__ __align__(16) u16 As[2][128 * 32];
  __shared__ __align__(16) u16 Bs[2][128 * 32];
  int tid = threadIdx.x;
  int m0 = blockIdx.y * 128, n0 = blockIdx.x * 128;
  int lane = tid & 63, wv = tid >> 6, wr = wv >> 1, wc = wv & 1;
  int lrow = lane & 15, quad = lane >> 4;
  int lr = lane >> 2;
  int lc = (((lane & 3) ^ ((lr >> 1) & 3)) * 8);  // XOR-swizzled source chunk
  int xq = quad ^ ((lrow >> 1) & 3);              // XOR-swizzled read chunk
  f32x4 acc[4][4];
#pragma unroll
  for (int i = 0; i < 4; ++i)
#pragma unroll
    for (int j = 0; j < 4; ++j) acc[i][j] = (f32x4){0.f, 0.f, 0.f, 0.f};

  const u16* Agb = A + (size_t)(m0 + wv * 32 + lr) * Kf + lc;
  const u16* Bgb = Bp + (size_t)(n0 + wv * 32 + lr) * Kf + lc;
  auto stage = [&](int k0, int b) {
    gl_lds16(Agb + k0,                     &As[b][(wv * 32) * 32]);
    gl_lds16(Agb + (size_t)16 * Kf + k0,   &As[b][(wv * 32 + 16) * 32]);
    gl_lds16(Bgb + k0,                     &Bs[b][(wv * 32) * 32]);
    gl_lds16(Bgb + (size_t)16 * Kf + k0,   &Bs[b][(wv * 32 + 16) * 32]);
  };
  int kb = slice * KS;
  int nIt = KS / 32;
  stage(kb, 0);
  __syncthreads();
  for (int it = 0; it < nIt; ++it) {
    int p = it & 1;
    if (it + 1 < nIt) stage(kb + (it + 1) * 32, p ^ 1);
    b16x8 af[4], bfr[4];
#pragma unroll
    for (int i = 0; i < 4; ++i) af[i] = *(const b16x8*)&As[p][(wr * 64 + i * 16 + lrow) * 32 + xq * 8];
#pragma unroll
    for (int j = 0; j < 4; ++j) bfr[j] = *(const b16x8*)&Bs[p][(wc * 64 + j * 16 + lrow) * 32 + xq * 8];
#pragma unroll
    for (int i = 0; i < 4; ++i)
#pragma unroll
      for (int j = 0; j < 4; ++j)
        acc[i][j] = __builtin_amdgcn_mfma_f32_16x16x32_bf16(af[i], bfr[j], acc[i][j], 0, 0, 0);
    __syncthreads();
  }
#pragma unroll
  for (int i = 0; i < 4; ++i)
#pragma unroll
    for (int j = 0; j < 4; ++j)
#pragma unroll
      for (int r = 0; r < 4; ++r) {
        int row = m0 + wr * 64 + i * 16 + quad * 4 + r;
        int col = n0 + wc * 64 + j * 16 + lrow;
        float val = acc[i][j][r];
        if (slice == 0 && resid) val += resid[(size_t)row * N + col];
        atomicAdd(&Cp[(size_t)row * N + col], val);
      }
}

// ---------------- fused gate/up GEMM + swiglu, dbuf + XCD swizzle, 128x64 tile ----------------
// grid 704: xcd = flat%8; idx = flat/8; m = idx%8 (8 row-blocks), n = xcd + 8*(idx/8) (88 strips).
// 4 waves, each 64(M)x32(N) per op: 4x2 mfma tiles x {g,u} = 16 mfma/iter.
__global__ __launch_bounds__(256) void k_gemm_gu(
    const u16* __restrict__ A, const u16* __restrict__ Bg, const u16* __restrict__ Bu,
    u16* __restrict__ D) {
  int flat = blockIdx.x;
  int xcd = flat & 7, idx = flat >> 3;
  int m = idx & 7, n = xcd + 8 * (idx >> 3);
  __shared__ __align__(16) u16 As[2][128 * 32];
  __shared__ __align__(16) u16 Gs[2][64 * 32];
  __shared__ __align__(16) u16 Us[2][64 * 32];
  int tid = threadIdx.x;
  int m0 = m * 128, n0 = n * 64;
  int lane = tid & 63, wv = tid >> 6, wr = wv >> 1, wc = wv & 1;
  int lrow = lane & 15, quad = lane >> 4;
  int lr = lane >> 2;
  int lc = (((lane & 3) ^ ((lr >> 1) & 3)) * 8);
  int xq = quad ^ ((lrow >> 1) & 3);
  f32x4 ag[4][2], au[4][2];
#pragma unroll
  for (int i = 0; i < 4; ++i)
#pragma unroll
    for (int j = 0; j < 2; ++j) { ag[i][j] = (f32x4){0.f, 0.f, 0.f, 0.f}; au[i][j] = (f32x4){0.f, 0.f, 0.f, 0.f}; }

  const u16* Agb = A + (size_t)(m0 + wv * 32 + lr) * HID + lc;
  const u16* Ggb = Bg + (size_t)(n0 + wv * 16 + lr) * HID + lc;
  const u16* Ugb = Bu + (size_t)(n0 + wv * 16 + lr) * HID + lc;
  auto stage = [&](int k0, int b) {
    gl_lds16(Agb + k0,                    &As[b][(wv * 32) * 32]);
    gl_lds16(Agb + (size_t)16 * HID + k0, &As[b][(wv * 32 + 16) * 32]);
    gl_lds16(Ggb + k0,                    &Gs[b][(wv * 16) * 32]);
    gl_lds16(Ugb + k0,                    &Us[b][(wv * 16) * 32]);
  };
  stage(0, 0);
  __syncthreads();
  for (int it = 0; it < HID / 32; ++it) {
    int p = it & 1;
    if (it + 1 < HID / 32) stage((it + 1) * 32, p ^ 1);
    b16x8 af[4], gf[2], uf[2];
#pragma unroll
    for (int i = 0; i < 4; ++i) af[i] = *(const b16x8*)&As[p][(wr * 64 + i * 16 + lrow) * 32 + xq * 8];
#pragma unroll
    for (int j = 0; j < 2; ++j) {
      gf[j] = *(const b16x8*)&Gs[p][(wc * 32 + j * 16 + lrow) * 32 + xq * 8];
      uf[j] = *(const b16x8*)&Us[p][(wc * 32 + j * 16 + lrow) * 32 + xq * 8];
    }
#pragma unroll
    for (int i = 0; i < 4; ++i)
#pragma unroll
      for (int j = 0; j < 2; ++j) {
        ag[i][j] = __builtin_amdgcn_mfma_f32_16x16x32_bf16(af[i], gf[j], ag[i][j], 0, 0, 0);
        au[i][j] = __builtin_amdgcn_mfma_f32_16x16x32_bf16(af[i], uf[j], au[i][j], 0, 0, 0);
      }
    __syncthreads();
  }
#pragma unroll
  for (int i = 0; i < 4; ++i)
#pragma unroll
    for (int j = 0; j < 2; ++j)
#pragma unroll
      for (int r = 0; r < 4; ++r) {
        int row = m0 + wr * 64 + i * 16 + quad * 4 + r;
        int col = n0 + wc * 32 + j * 16 + lrow;
        D[(size_t)row * INTER + col] = f2bf(silu_f(ag[i][j][r]) * au[i][j][r]);
      }
}

// ---------------- beta = sigmoid(h @ Wbeta^T) ----------------
__global__ __launch_bounds__(256) void k_beta(const u16* __restrict__ hbf, const float* __restrict__ Wb,
                                              float* __restrict__ beta) {
  __shared__ __align__(16) float hr[HID];
  __shared__ float red[256];
  int t = blockIdx.x, tid = threadIdx.x;
#pragma unroll
  for (int i = 0; i < 8; ++i) {
    int c = i * 256 + tid;
    hr[c] = bf2f(hbf[(size_t)t * HID + c]);
  }
  __syncthreads();
  int head = tid >> 3, j = tid & 7;
  const float* wrow = Wb + (size_t)head * HID + j * 256;
  const float* hs = hr + j * 256;
  float acc = 0.f;
#pragma unroll 16
  for (int c = 0; c < 256; c += 4) {
    float4 wv = *(const float4*)&wrow[c];
    float4 hv = *(const float4*)&hs[c];
    acc += hv.x * wv.x + hv.y * wv.y + hv.z * wv.z + hv.w * wv.w;
  }
  red[tid] = acc;
  __syncthreads();
  if (tid < 32) {
    float s = 0.f;
#pragma unroll
    for (int i = 0; i < 8; ++i) s += red[tid * 8 + i];
    beta[(size_t)t * NH + tid] = 1.f / (1.f + __expf(-s));
  }
}

// ---------------- causal depthwise conv (K=4) + silu(silu) (+ l2norm for q,k) ----------------
__global__ __launch_bounds__(256) void k_conv(const float* __restrict__ proj,
                                              const float* __restrict__ cw0, const float* __restrict__ cw1,
                                              const float* __restrict__ cw2, float* __restrict__ outp) {
  int z = blockIdx.z;
  const float* src = proj + (size_t)z * T_SEQ * HID;
  float* dst = outp + (size_t)z * T_SEQ * HID;
  const float* cw = (z == 0) ? cw0 : (z == 1 ? cw1 : cw2);
  bool l2 = (z < 2);
  int c = threadIdx.x & 63, wr = threadIdx.x >> 6;
  int head = blockIdx.y;
  int ch = head * 64 + c;
  int t0 = blockIdx.x * 64 + wr * 16;
  float4 w = ((const float4*)cw)[ch];
  float xm3 = (t0 >= 3) ? src[(size_t)(t0 - 3) * HID + ch] : 0.f;
  float xm2 = (t0 >= 2) ? src[(size_t)(t0 - 2) * HID + ch] : 0.f;
  float xm1 = (t0 >= 1) ? src[(size_t)(t0 - 1) * HID + ch] : 0.f;
  for (int i = 0; i < 16; ++i) {
    int t = t0 + i;
    float x0 = src[(size_t)t * HID + ch];
    float zv = xm3 * w.x + xm2 * w.y + xm1 * w.z + x0 * w.w;
    float s = silu_f(silu_f(zv));
    if (l2) {
      float ss = s * s;
      for (int m = 32; m; m >>= 1) ss += __shfl_xor(ss, m, 64);
      float n = sqrtf(ss);
      s = s / fmaxf(n, 1e-12f);
    }
    dst[(size_t)t * HID + ch] = s;
    xm3 = xm2; xm2 = xm1; xm1 = x0;
  }
}

// ---------------- Phase A ----------------
__global__ __launch_bounds__(256) void k_phaseA(
    const float* __restrict__ qp, const float* __restrict__ kp, const float* __restrict__ vp,
    const float* __restrict__ beta,
    u16* __restrict__ negWbf, u16* __restrict__ Uvbf, u16* __restrict__ Ktbf,
    u16* __restrict__ Qbf, u16* __restrict__ Pbf) {
  int cx = blockIdx.x, h = blockIdx.y;
  __shared__ __align__(16) u16 Kst[64 * 72];
  __shared__ __align__(16) u16 Qst[64 * 72];
  __shared__ __align__(16) float Af[64 * 68];
  __shared__ float bet[64];
  int tid = threadIdx.x;
  int t0 = cx * 64;
#pragma unroll
  for (int i = 0; i < 16; ++i) {
    int idx = i * 256 + tid, s = idx >> 6, d = idx & 63;
    size_t g = (size_t)(t0 + s) * HID + h * 64 + d;
    Kst[s * 72 + d] = f2bf(kp[g]);
    Qst[s * 72 + d] = f2bf(qp[g]);
  }
  if (tid < 64) bet[tid] = beta[(size_t)(t0 + tid) * NH + h];
  __syncthreads();
  int lane = tid & 63, wv = tid >> 6, lrow = lane & 15, quad = lane >> 4;
  f32x4 accA[4], accP[4];
#pragma unroll
  for (int i = 0; i < 4; ++i) { accA[i] = (f32x4){0.f, 0.f, 0.f, 0.f}; accP[i] = (f32x4){0.f, 0.f, 0.f, 0.f}; }
#pragma unroll
  for (int ks = 0; ks < 2; ++ks) {
    b16x8 bk = *(const b16x8*)&Kst[(wv * 16 + lrow) * 72 + ks * 32 + quad * 8];
#pragma unroll
    for (int i = 0; i < 4; ++i) {
      b16x8 ak = *(const b16x8*)&Kst[(i * 16 + lrow) * 72 + ks * 32 + quad * 8];
      b16x8 aq = *(const b16x8*)&Qst[(i * 16 + lrow) * 72 + ks * 32 + quad * 8];
      accA[i] = __builtin_amdgcn_mfma_f32_16x16x32_bf16(ak, bk, accA[i], 0, 0, 0);
      accP[i] = __builtin_amdgcn_mfma_f32_16x16x32_bf16(aq, bk, accP[i], 0, 0, 0);
    }
  }
  size_t cb2 = ((size_t)h * NCHUNK + cx) * 4096;
#pragma unroll
  for (int i = 0; i < 4; ++i)
#pragma unroll
    for (int r = 0; r < 4; ++r) {
      int srow = i * 16 + quad * 4 + r, col = wv * 16 + lrow;
      Af[srow * 68 + col] = (col < srow) ? accA[i][r] * bet[srow] : 0.f;
      Pbf[cb2 + srow * 64 + col] = f2bf((col <= srow) ? accP[i][r] : 0.f);
    }
  __syncthreads();
  if (wv < 2) {
    int c = lane;
    float x[64];
    if (wv == 0) {
#pragma unroll
      for (int s = 0; s < 64; ++s) x[s] = bet[s] * bf2f(Kst[s * 72 + c]);
    } else {
#pragma unroll
      for (int s = 0; s < 64; ++s) x[s] = bet[s] * vp[(size_t)(t0 + s) * HID + h * 64 + c];
    }
#pragma unroll
    for (int s = 1; s < 64; ++s) {
      float a = 0.f;
#pragma unroll
      for (int r = 0; r < (s & ~3); r += 4) {
        float4 av = *(const float4*)&Af[s * 68 + r];
        a += av.x * x[r] + av.y * x[r + 1] + av.z * x[r + 2] + av.w * x[r + 3];
      }
#pragma unroll
      for (int r = (s & ~3); r < s; ++r) a += Af[s * 68 + r] * x[r];
      x[s] -= a;
    }
    if (wv == 0) {
#pragma unroll
      for (int s = 0; s < 64; ++s) negWbf[cb2 + s * 64 + c] = f2bf(-x[s]);
    } else {
#pragma unroll
      for (int s = 0; s < 64; ++s) Uvbf[cb2 + s * 64 + c] = f2bf(x[s]);
    }
  } else if (wv == 2) {
#pragma unroll
    for (int it = 0; it < 8; ++it) {
      int cidx = it * 64 + lane, s = cidx >> 3, d0 = (cidx & 7) * 8;
      *(uint4*)&Qbf[cb2 + s * 64 + d0] = *(const uint4*)&Qst[s * 72 + d0];
    }
  } else {
#pragma unroll
    for (int it = 0; it < 8; ++it) {
      int cidx = it * 64 + lane, d = cidx >> 3, s0 = (cidx & 7) * 8;
      u16 tmp[8];
#pragma unroll
      for (int j = 0; j < 8; ++j) tmp[j] = Kst[(s0 + j) * 72 + d];
      *(uint4*)&Ktbf[cb2 + d * 64 + s0] = *(const uint4*)tmp;
    }
  }
}

// ---------------- Phase B1: serial per head ----------------
__global__ __launch_bounds__(256) void k_phaseB1(
    const u16* __restrict__ negWbf, const u16* __restrict__ Uvbf, const u16* __restrict__ Ktbf,
    u16* __restrict__ Utws, u16* __restrict__ Sws, float* __restrict__ Sout) {
  int h = blockIdx.x, tid = threadIdx.x;
  __shared__ __align__(16) u16 S0b[2][64 * 72];
  __shared__ __align__(16) u16 Ut[64 * 72];
  int lane = tid & 63, wv = tid >> 6, lrow = lane & 15, quad = lane >> 4;
#pragma unroll
  for (int i = 0; i < 16; ++i) {
    int idx = i * 256 + tid;
    S0b[0][(idx >> 6) * 72 + (idx & 63)] = 0;
  }
  f32x4 aS[4];
#pragma unroll
  for (int i = 0; i < 4; ++i) aS[i] = (f32x4){0.f, 0.f, 0.f, 0.f};

  b16x8 Wf[2][4][2]; b16x8 Ktf[2][2]; u16 Uvr[2][4][4];
  size_t hb = (size_t)h * NCHUNK * 4096;
  {
    size_t cb2 = hb;
#pragma unroll
    for (int i = 0; i < 4; ++i)
#pragma unroll
      for (int ks = 0; ks < 2; ++ks)
        Wf[0][i][ks] = *(const b16x8*)&negWbf[cb2 + (i * 16 + lrow) * 64 + ks * 32 + quad * 8];
#pragma unroll
    for (int ks = 0; ks < 2; ++ks)
      Ktf[0][ks] = *(const b16x8*)&Ktbf[cb2 + (wv * 16 + lrow) * 64 + ks * 32 + quad * 8];
#pragma unroll
    for (int i = 0; i < 4; ++i)
#pragma unroll
      for (int r = 0; r < 4; ++r)
        Uvr[0][i][r] = Uvbf[cb2 + (i * 16 + quad * 4 + r) * 64 + wv * 16 + lrow];
  }
  __syncthreads();
#pragma unroll
  for (int cx = 0; cx < NCHUNK; ++cx) {
    const int p = cx & 1, q = p ^ 1;
    size_t cb2 = hb + (size_t)cx * 4096;
    if (cx > 0) {
#pragma unroll
      for (int i = 0; i < 2; ++i) {
        int cidx = i * 256 + tid, dv = cidx >> 3, s0 = (cidx & 7) * 8;
        *(uint4*)&Sws[cb2 + dv * 64 + s0] = *(const uint4*)&S0b[p][dv * 72 + s0];
      }
    }
    if (cx + 1 < NCHUNK) {
      size_t cbn = cb2 + 4096;
#pragma unroll
      for (int i = 0; i < 4; ++i)
#pragma unroll
        for (int ks = 0; ks < 2; ++ks)
          Wf[q][i][ks] = *(const b16x8*)&negWbf[cbn + (i * 16 + lrow) * 64 + ks * 32 + quad * 8];
#pragma unroll
      for (int ks = 0; ks < 2; ++ks)
        Ktf[q][ks] = *(const b16x8*)&Ktbf[cbn + (wv * 16 + lrow) * 64 + ks * 32 + quad * 8];
#pragma unroll
      for (int i = 0; i < 4; ++i)
#pragma unroll
        for (int r = 0; r < 4; ++r)
          Uvr[q][i][r] = Uvbf[cbn + (i * 16 + quad * 4 + r) * 64 + wv * 16 + lrow];
    }
    f32x4 aU[4];
#pragma unroll
    for (int i = 0; i < 4; ++i)
#pragma unroll
      for (int r = 0; r < 4; ++r) aU[i][r] = bf2f(Uvr[p][i][r]);
#pragma unroll
    for (int ks = 0; ks < 2; ++ks) {
      b16x8 bS = *(const b16x8*)&S0b[p][(wv * 16 + lrow) * 72 + ks * 32 + quad * 8];
#pragma unroll
      for (int i = 0; i < 4; ++i)
        aU[i] = __builtin_amdgcn_mfma_f32_16x16x32_bf16(Wf[p][i][ks], bS, aU[i], 0, 0, 0);
    }
#pragma unroll
    for (int i = 0; i < 4; ++i)
#pragma unroll
      for (int r = 0; r < 4; ++r) {
        int s = i * 16 + quad * 4 + r, dv = wv * 16 + lrow;
        Ut[dv * 72 + s] = f2bf(aU[i][r]);
      }
    __syncthreads();
#pragma unroll
    for (int i = 0; i < 2; ++i) {
      int cidx = i * 256 + tid, dv = cidx >> 3, s0 = (cidx & 7) * 8;
      *(uint4*)&Utws[cb2 + dv * 64 + s0] = *(const uint4*)&Ut[dv * 72 + s0];
    }
#pragma unroll
    for (int ks = 0; ks < 2; ++ks) {
#pragma unroll
      for (int i = 0; i < 4; ++i) {
        b16x8 a = *(const b16x8*)&Ut[(i * 16 + lrow) * 72 + ks * 32 + quad * 8];
        aS[i] = __builtin_amdgcn_mfma_f32_16x16x32_bf16(a, Ktf[p][ks], aS[i], 0, 0, 0);
      }
    }
#pragma unroll
    for (int i = 0; i < 4; ++i)
#pragma unroll
      for (int r = 0; r < 4; ++r) {
        int dv = i * 16 + quad * 4 + r, dk = wv * 16 + lrow;
        S0b[q][dv * 72 + dk] = f2bf(aS[i][r]);
      }
    __syncthreads();
  }
#pragma unroll
  for (int i = 0; i < 4; ++i)
#pragma unroll
    for (int r = 0; r < 4; ++r) {
      int dv = i * 16 + quad * 4 + r, dk = wv * 16 + lrow;
      Sout[(size_t)h * 4096 + dv * 64 + dk] = aS[i][r];
    }
}

// ---------------- Phase B2: parallel O = Q S^T + P U ----------------
__global__ __launch_bounds__(256) void k_phaseB2(
    const u16* __restrict__ Qbf, const u16* __restrict__ Pbf,
    const u16* __restrict__ Utws, const u16* __restrict__ Sws, float* __restrict__ o) {
  int cx = blockIdx.x, h = blockIdx.y, tid = threadIdx.x;
  int lane = tid & 63, wv = tid >> 6, lrow = lane & 15, quad = lane >> 4;
  size_t cb2 = ((size_t)h * NCHUNK + cx) * 4096;
  f32x4 aO[4];
#pragma unroll
  for (int i = 0; i < 4; ++i) aO[i] = (f32x4){0.f, 0.f, 0.f, 0.f};
#pragma unroll
  for (int ks = 0; ks < 2; ++ks) {
    b16x8 Uf = *(const b16x8*)&Utws[cb2 + (wv * 16 + lrow) * 64 + ks * 32 + quad * 8];
#pragma unroll
    for (int i = 0; i < 4; ++i) {
      b16x8 Pf = *(const b16x8*)&Pbf[cb2 + (i * 16 + lrow) * 64 + ks * 32 + quad * 8];
      aO[i] = __builtin_amdgcn_mfma_f32_16x16x32_bf16(Pf, Uf, aO[i], 0, 0, 0);
    }
  }
  if (cx > 0) {
#pragma unroll
    for (int ks = 0; ks < 2; ++ks) {
      b16x8 Sf = *(const b16x8*)&Sws[cb2 + (wv * 16 + lrow) * 64 + ks * 32 + quad * 8];
#pragma unroll
      for (int i = 0; i < 4; ++i) {
        b16x8 Qf = *(const b16x8*)&Qbf[cb2 + (i * 16 + lrow) * 64 + ks * 32 + quad * 8];
        aO[i] = __builtin_amdgcn_mfma_f32_16x16x32_bf16(Qf, Sf, aO[i], 0, 0, 0);
      }
    }
  }
  int t0 = cx * 64;
#pragma unroll
  for (int i = 0; i < 4; ++i)
#pragma unroll
    for (int r = 0; r < 4; ++r)
      o[(size_t)(t0 + i * 16 + quad * 4 + r) * HID + h * 64 + wv * 16 + lrow] = aO[i][r];
}

extern "C" void kernel_launch(void* const* d_in, const int* in_sizes, int n_in,
                              void* d_out, int out_size, void* d_ws, size_t ws_size,
                              hipStream_t stream) {
  const float* x     = (const float*)d_in[0];
  const float* anw   = (const float*)d_in[1];
  const float* Wq    = (const float*)d_in[2];
  const float* Wk    = (const float*)d_in[3];
  const float* Wv    = (const float*)d_in[4];
  const float* convq = (const float*)d_in[5];
  const float* convk = (const float*)d_in[6];
  const float* convv = (const float*)d_in[7];
  const float* Wbeta = (const float*)d_in[8];
  const float* onw   = (const float*)d_in[9];
  const float* Wout  = (const float*)d_in[10];
  const float* mnw   = (const float*)d_in[11];
  const float* Wgate = (const float*)d_in[12];
  const float* Wup   = (const float*)d_in[13];
  const float* Wdown = (const float*)d_in[14];
  float* out = (float*)d_out;

  const size_t TH = (size_t)T_SEQ * HID;
  const size_t SCAN = (size_t)NH * NCHUNK * 4096;
  char* wsb = (char*)d_ws;
  size_t off = 0;
  auto alloc = [&](size_t bytes) -> void* {
    void* p = wsb + off;
    off += (bytes + 255) & ~(size_t)255;
    return p;
  };
  u16* wq_bf    = (u16*)alloc((size_t)HID * HID * 2);
  u16* wk_bf    = (u16*)alloc((size_t)HID * HID * 2);
  u16* wv_bf    = (u16*)alloc((size_t)HID * HID * 2);
  u16* wout_bf  = (u16*)alloc((size_t)HID * HID * 2);
  u16* wgate_bf = (u16*)alloc((size_t)INTER * HID * 2);
  u16* wup_bf   = (u16*)alloc((size_t)INTER * HID * 2);
  u16* wdown_bf = (u16*)alloc((size_t)HID * INTER * 2);
  u16* actbf    = (u16*)alloc(TH * 2);
  float* qkv_proj = (float*)alloc(3 * TH * 4);   // aliased later: obuf
  float* qkvpost  = (float*)alloc(3 * TH * 4);
  float* betab    = (float*)alloc((size_t)T_SEQ * NH * 4);
  u16* negWbf = (u16*)alloc(SCAN * 2);           // aliased later by g_bf
  u16* Uvbf   = (u16*)alloc(SCAN * 2);
  u16* Ktbf   = (u16*)alloc(SCAN * 2);
  u16* Qbf    = (u16*)alloc(SCAN * 2);
  u16* Pbf    = (u16*)alloc(SCAN * 2);
  u16* Utws   = (u16*)alloc(SCAN * 2);
  u16* Sws    = (u16*)alloc(SCAN * 2);
  float* x1   = (float*)alloc(TH * 4);
  float* obuf = qkv_proj;   // qkv_proj dead after conv
  u16* g_bf   = negWbf;     // scan buffers dead after B2 (11.5MB < 3x4.19MB)

  // ---- zero all atomic targets up front ----
  hipMemsetAsync(qkv_proj, 0, 3 * TH * 4, stream);
  hipMemsetAsync(x1, 0, TH * 4, stream);
  hipMemsetAsync(out, 0, TH * 4, stream);

  // ---- all weight conversions in one launch ----
  k_cvt_all<<<dim3(INTER * HID / 4 / 256, 7), 256, 0, stream>>>(
      Wq, Wk, Wv, Wout, Wgate, Wup, Wdown,
      wq_bf, wk_bf, wv_bf, wout_bf, wgate_bf, wup_bf, wdown_bf);

  k_rms<<<dim3(T_SEQ), 256, 0, stream>>>(x, anw, actbf);
  // qkv projections: splitK=2 (768 blocks = 3/CU), atomic into zeroed qkv_proj
  k_gemm_sk<<<dim3(HID / 128, T_SEQ / 128, 6), 256, 0, stream>>>(
      actbf, wq_bf, wk_bf, wv_bf, qkv_proj, qkv_proj + TH, qkv_proj + 2 * TH, nullptr,
      T_SEQ, HID, HID, HID / 2, 2);
  k_beta<<<dim3(T_SEQ), 256, 0, stream>>>(actbf, Wbeta, betab);
  k_conv<<<dim3(T_SEQ / 64, NH, 3), 256, 0, stream>>>(qkv_proj, convq, convk, convv, qkvpost);
  k_phaseA<<<dim3(NCHUNK, NH), 256, 0, stream>>>(
      qkvpost, qkvpost + TH, qkvpost + 2 * TH, betab, negWbf, Uvbf, Ktbf, Qbf, Pbf);
  k_phaseB1<<<dim3(NH), 256, 0, stream>>>(negWbf, Uvbf, Ktbf, Utws, Sws, out + TH);
  k_phaseB2<<<dim3(NCHUNK, NH), 256, 0, stream>>>(Qbf, Pbf, Utws, Sws, obuf);
  k_rms<<<dim3(T_SEQ), 256, 0, stream>>>(obuf, onw, actbf);
  // out projection: splitK=4 (512 blocks = 2/CU), resid=x, atomic into zeroed x1
  k_gemm_sk<<<dim3(HID / 128, T_SEQ / 128, 4), 256, 0, stream>>>(
      actbf, wout_bf, wout_bf, wout_bf, x1, x1, x1, x, T_SEQ, HID, HID, HID / 4, 4);
  k_rms<<<dim3(T_SEQ), 256, 0, stream>>>(x1, mnw, actbf);
  // fused gate/up + swiglu -> bf16 (704-block XCD-swizzled grid, 128x64 tiles)
  k_gemm_gu<<<dim3(704), 256, 0, stream>>>(actbf, wgate_bf, wup_bf, g_bf);
  // down projection: splitK=4 (512 blocks = 2/CU), resid=x1, atomic into zeroed out
  k_gemm_sk<<<dim3(HID / 128, T_SEQ / 128, 4), 256, 0, stream>>>(
      g_bf, wdown_bf, wdown_bf, wdown_bf, out, out, out, x1, T_SEQ, HID, INTER, INTER / 4, 4);
}